// Round 8
// baseline (567.529 us; speedup 1.0000x reference)
//
#include <hip/hip_runtime.h>

typedef __bf16 bf16x8 __attribute__((ext_vector_type(8)));
typedef float f32x16 __attribute__((ext_vector_type(16)));
typedef unsigned int u32x4 __attribute__((ext_vector_type(4)));

#define NGROUP 8
#define DMODEL 256
#define DFF    1024
#define TTOT   131072
#define TGRP   (TTOT / NGROUP)   // 16384
#define NCHUNK 32                // f-chunks of 32 (DFF/32)

// ======================= SPLIT DESIGN (sync fixed) =======================
//  k_gemm1: z=x@W{g,u}, h=silu*up -> h (bf16, MFMA-frag layout) to workspace.
//           64 tok/wave -> each LDS weight read feeds 2 MFMAs (MFMA-bound).
//           SYNC: R5-proven double-buffer, ONE vmcnt(0)+barrier per chunk.
//           (R7 bug: counted vmcnt over a mixed load/STORE FIFO -- stores
//           retire out of order vs loads, so vmcnt(12) could pass with the
//           current chunk's staging still in flight.)
//  k_gemm2: y = h @ Wd. Wave tile 128tok x 64d; triple-buffer + counted
//           vmcnt(4) (load-only stream => in-order, sound), tail c==31 fixed
//           to vmcnt(0).
// ws = wcomb (12.6MB) + h (268MB).  If ws_size too small -> R5 fused fallback.

__device__ __forceinline__ unsigned int f2bf(float f) {
    unsigned int x = __builtin_bit_cast(unsigned int, f);
    return (x + 0x7fffu + ((x >> 16) & 1u)) >> 16;   // RNE
}
__device__ __forceinline__ unsigned int pack2(float lo, float hi) {
    return f2bf(lo) | (f2bf(hi) << 16);
}
__device__ __forceinline__ unsigned int cvtpk(float lo, float hi) {
    unsigned int r;
    asm("v_cvt_pk_bf16_f32 %0, %1, %2" : "=v"(r) : "v"(lo), "v"(hi));  // RNE
    return r;
}

__device__ __forceinline__ void g2l(const void* g, void* l) {
    __builtin_amdgcn_global_load_lds(
        (const __attribute__((address_space(1))) unsigned int*)g,
        (__attribute__((address_space(3))) unsigned int*)l, 16, 0, 0);
}

#define MFMA(A, B, C) __builtin_amdgcn_mfma_f32_32x32x16_bf16( \
        __builtin_bit_cast(bf16x8, A), __builtin_bit_cast(bf16x8, B), C, 0, 0, 0)

// ---------------- prep: all weights -> per-(group,chunk) 48KB frag blocks ----------------
//   fid 0..15  : gate A-frag, ks=fid      W[d=ks*16+q*8+j][f=c*32+l31]
//   fid 16..31 : up   A-frag, ks=fid-16
//   fid 32..47 : down B-frag, ks2=(fid-32)>>3, nb=(fid-32)&7
//     k-axis PERMUTED to match packed-accumulator A-frags:
//     B[k=q*8+j] = Wd[F = c*32 + ks2*16 + q*4 + (j&3) + 8*(j>>2)][col=nb*32+l31]
__global__ void k_prep_w(const float* __restrict__ wg, const float* __restrict__ wu,
                         const float* __restrict__ wd, u32x4* __restrict__ out) {
    int t = blockIdx.x * 256 + threadIdx.x;   // 786432 total
    int lane = t & 63;
    int q = lane >> 5, l31 = lane & 31;
    int fg = t >> 6;
    int fid = fg % 48;
    int gc  = fg / 48;
    int c = gc & 31, g = gc >> 5;
    u32x4 v;
    if (fid < 32) {
        const float* w = (fid < 16) ? wg : wu;
        int ks = fid & 15;
        const float* src = w + (size_t)(g * 256 + ks * 16 + q * 8) * 1024 + c * 32 + l31;
        v = u32x4{ pack2(src[0],        src[1024]),
                   pack2(src[2 * 1024], src[3 * 1024]),
                   pack2(src[4 * 1024], src[5 * 1024]),
                   pack2(src[6 * 1024], src[7 * 1024]) };
    } else {
        int idx = fid - 32;
        int ks2 = idx >> 3, nb = idx & 7;
        const float* src = wd + (size_t)(g * 1024 + c * 32 + ks2 * 16 + q * 4) * 256 + nb * 32 + l31;
        v = u32x4{ pack2(src[0 * 256],  src[1 * 256]),
                   pack2(src[2 * 256],  src[3 * 256]),
                   pack2(src[8 * 256],  src[9 * 256]),
                   pack2(src[10 * 256], src[11 * 256]) };
    }
    out[t] = v;
}

// ---------------- k_gemm1: gate/up GEMM + silu, h -> workspace ----------------
// 256 blocks x 512 thr; block = 512 tokens; wave = 64 tokens (2 x 32-tok blocks).
// LDS 64KB: two 32KB gate+up buffers; 1 vmcnt(0)+barrier per chunk (R5 pattern).
__global__ __launch_bounds__(512, 2)
void k_gemm1(const float* __restrict__ x, const u32x4* __restrict__ wcomb,
             u32x4* __restrict__ hout) {
    __shared__ u32x4 smem[4096];   // 64 KB: two 32KB buffers

    const int tid  = threadIdx.x;
    const int lane = tid & 63;
    const int w    = tid >> 6;      // 0..7
    const int q    = lane >> 5;
    const int l31  = lane & 31;

    const int g    = blockIdx.x & 7;
    const int m0   = g * TGRP + (blockIdx.x >> 3) * 512;
    const int tok0 = m0 + w * 64 + l31;
    const int tok1 = tok0 + 32;
    const size_t tb0 = (size_t)((m0 >> 5) + w * 2);   // global 32-tok block index

    const u32x4* wcg = wcomb + (size_t)(g * 32) * 3072;

    // prologue: stage chunk0 -> buf0 (gate+up = first 2048 u32x4 of the 3072)
    #pragma unroll
    for (int i = 0; i < 4; ++i) {
        int off = i * 512 + w * 64;
        g2l(wcg + off + lane, smem + off);
    }

    // x -> bf16 B-frags for both token blocks (128 VGPR)
    u32x4 xf0[16], xf1[16];
    {
        const float* xr0 = x + (size_t)tok0 * DMODEL + q * 8;
        const float* xr1 = x + (size_t)tok1 * DMODEL + q * 8;
        #pragma unroll
        for (int ks = 0; ks < 16; ++ks) {
            float4 a = *(const float4*)(xr0 + ks * 16);
            float4 b = *(const float4*)(xr0 + ks * 16 + 4);
            xf0[ks] = u32x4{ cvtpk(a.x, a.y), cvtpk(a.z, a.w),
                             cvtpk(b.x, b.y), cvtpk(b.z, b.w) };
            float4 e = *(const float4*)(xr1 + ks * 16);
            float4 d = *(const float4*)(xr1 + ks * 16 + 4);
            xf1[ks] = u32x4{ cvtpk(e.x, e.y), cvtpk(e.z, e.w),
                             cvtpk(d.x, d.y), cvtpk(d.z, d.w) };
        }
    }

    for (int c = 0; c < NCHUNK; ++c) {
        const u32x4* sbc = smem + (c & 1) * 2048;

        asm volatile("s_waitcnt vmcnt(0)" ::: "memory");   // stage(c) + old stores drained
        __builtin_amdgcn_s_barrier();                      // all waves done reading other buf
        asm volatile("" ::: "memory");

        // stage chunk c+1 into the other buffer (full compute phase of slack)
        if (c + 1 < NCHUNK) {
            u32x4* db = smem + ((c + 1) & 1) * 2048;
            const u32x4* gsrc = wcg + (size_t)(c + 1) * 3072;
            #pragma unroll
            for (int i = 0; i < 4; ++i) {
                int off = i * 512 + w * 64;
                g2l(gsrc + off + lane, db + off);
            }
        }

        // GEMM1: each weight read feeds BOTH token blocks (2 reads : 4 MFMA)
        f32x16 zg0, zu0, zg1, zu1;
        #pragma unroll
        for (int i = 0; i < 16; ++i) { zg0[i] = 0.0f; zu0[i] = 0.0f; zg1[i] = 0.0f; zu1[i] = 0.0f; }
        __builtin_amdgcn_s_setprio(1);
        #pragma unroll
        for (int ks = 0; ks < 16; ++ks) {
            const u32x4 a1 = sbc[ks * 64 + lane];          // gate
            const u32x4 a2 = sbc[1024 + ks * 64 + lane];   // up
            zg0 = MFMA(a1, xf0[ks], zg0);
            zg1 = MFMA(a1, xf1[ks], zg1);
            zu0 = MFMA(a2, xf0[ks], zu0);
            zu1 = MFMA(a2, xf1[ks], zu1);
        }
        __builtin_amdgcn_s_setprio(0);

        // act + pack (frag layout identical to fused version's A0/A1)
        u32x4 A00, A01, A10, A11;
        {
            float hv[16];
            #pragma unroll
            for (int i = 0; i < 16; ++i) {
                const float gv = zg0[i];
                const float s  = __builtin_amdgcn_rcpf(1.0f + __expf(-gv));
                hv[i] = gv * s * zu0[i];
            }
            A00 = u32x4{ cvtpk(hv[0], hv[1]),   cvtpk(hv[2], hv[3]),
                         cvtpk(hv[4], hv[5]),   cvtpk(hv[6], hv[7]) };
            A01 = u32x4{ cvtpk(hv[8], hv[9]),   cvtpk(hv[10], hv[11]),
                         cvtpk(hv[12], hv[13]), cvtpk(hv[14], hv[15]) };
            #pragma unroll
            for (int i = 0; i < 16; ++i) {
                const float gv = zg1[i];
                const float s  = __builtin_amdgcn_rcpf(1.0f + __expf(-gv));
                hv[i] = gv * s * zu1[i];
            }
            A10 = u32x4{ cvtpk(hv[0], hv[1]),   cvtpk(hv[2], hv[3]),
                         cvtpk(hv[4], hv[5]),   cvtpk(hv[6], hv[7]) };
            A11 = u32x4{ cvtpk(hv[8], hv[9]),   cvtpk(hv[10], hv[11]),
                         cvtpk(hv[12], hv[13]), cvtpk(hv[14], hv[15]) };
        }

        // store h frags: [tokblk][slot=2c+ks2][lane] x 16B (coalesced 1KB groups)
        u32x4* hp = hout + (tb0 * 64 + 2 * c) * 64 + lane;
        hp[0]    = A00;
        hp[64]   = A01;
        hp[4096] = A10;   // tokblk+1: +64*64
        hp[4160] = A11;
    }
}

// ---------------- k_gemm2: y = h @ Wd ----------------
// 512 blocks x 512 thr; block = 256 tok x 256 d; wave = 128 tok x 64 d.
// LDS 96KB: three 32KB buffers [h 16 frag-groups | Wd 16 frag-groups].
// In-loop vmem stream is LOAD-ONLY (g2l) -> counted vmcnt(4) is sound;
// tail c==NCHUNK-1 must drain (stage(31) is the newest 4 and otherwise unguarded).
__global__ __launch_bounds__(512, 2)
void k_gemm2(const u32x4* __restrict__ hbuf, const u32x4* __restrict__ wcomb,
             float* __restrict__ y) {
    __shared__ u32x4 smem[6144];   // 96 KB

    const int tid  = threadIdx.x;
    const int lane = tid & 63;
    const int w    = tid >> 6;      // 0..7
    const int q    = lane >> 5;
    const int l31  = lane & 31;
    const int wr   = w >> 2;        // token half (128)
    const int wc   = w & 3;         // d quarter (64)

    const int g  = blockIdx.x & 7;
    const int mb = blockIdx.x >> 3;            // 0..63
    const int m0 = g * TGRP + mb * 256;
    const int TB0 = m0 >> 5;                   // base 32-tok block

    const u32x4* wcg = wcomb + (size_t)(g * 32) * 3072;

    // staging: 32 frag-groups/chunk (h 16 + Wd 16), 4 per wave; dst = buf + j*64
    auto stage = [&](int c, u32x4* buf) {
        #pragma unroll
        for (int i = 0; i < 4; ++i) {
            const int j = w * 4 + i;
            const u32x4* src = (j < 16)
                ? hbuf + ((size_t)(TB0 + (j >> 1)) * 64 + 2 * c + (j & 1)) * 64
                : wcg + (size_t)c * 3072 + 2048 + (size_t)(j - 16) * 64;
            g2l(src + lane, buf + j * 64);
        }
    };

    stage(0, smem);
    stage(1, smem + 2048);

    f32x16 acc[8];   // [tb*2+db], tb 0..3, db 0..1
    #pragma unroll
    for (int t = 0; t < 8; ++t)
        #pragma unroll
        for (int i = 0; i < 16; ++i) acc[t][i] = 0.0f;

    int bc = 0;
    for (int c = 0; c < NCHUNK; ++c) {
        const u32x4* sb = smem + bc * 2048;

        if (c < NCHUNK - 1) {
            asm volatile("s_waitcnt vmcnt(4)" ::: "memory");  // stage(c) done; stage(c+1) in flight
        } else {
            asm volatile("s_waitcnt vmcnt(0)" ::: "memory");  // tail: stage(31) unguarded otherwise
        }
        __builtin_amdgcn_s_barrier();
        asm volatile("" ::: "memory");

        if (c + 2 < NCHUNK) {
            const int bn = (bc + 2 >= 3) ? bc - 1 : bc + 2;
            stage(c + 2, smem + bn * 2048);
        }

        __builtin_amdgcn_s_setprio(1);
        #pragma unroll
        for (int ks2 = 0; ks2 < 2; ++ks2) {
            const u32x4 ha0 = sb[((wr * 4 + 0) * 2 + ks2) * 64 + lane];
            const u32x4 ha1 = sb[((wr * 4 + 1) * 2 + ks2) * 64 + lane];
            const u32x4 ha2 = sb[((wr * 4 + 2) * 2 + ks2) * 64 + lane];
            const u32x4 ha3 = sb[((wr * 4 + 3) * 2 + ks2) * 64 + lane];
            const u32x4 bd0 = sb[1024 + (ks2 * 8 + wc * 2 + 0) * 64 + lane];
            const u32x4 bd1 = sb[1024 + (ks2 * 8 + wc * 2 + 1) * 64 + lane];
            acc[0] = MFMA(ha0, bd0, acc[0]);
            acc[1] = MFMA(ha0, bd1, acc[1]);
            acc[2] = MFMA(ha1, bd0, acc[2]);
            acc[3] = MFMA(ha1, bd1, acc[3]);
            acc[4] = MFMA(ha2, bd0, acc[4]);
            acc[5] = MFMA(ha2, bd1, acc[5]);
            acc[6] = MFMA(ha3, bd0, acc[6]);
            acc[7] = MFMA(ha3, bd1, acc[7]);
        }
        __builtin_amdgcn_s_setprio(0);

        bc = (bc == 2) ? 0 : bc + 1;
    }

    // epilogue: 8 tiles, C layout -> y fp32
    #pragma unroll
    for (int tb = 0; tb < 4; ++tb) {
        #pragma unroll
        for (int db = 0; db < 2; ++db) {
            float* yp = y + (size_t)(m0 + wr * 128 + tb * 32) * DMODEL + wc * 64 + db * 32;
            const f32x16 a = acc[tb * 2 + db];
            #pragma unroll
            for (int r = 0; r < 16; ++r) {
                const int row = (r & 3) + (r >> 2) * 8 + q * 4;
                yp[(size_t)row * DMODEL + l31] = a[r];
            }
        }
    }
}

// ---------------- fallback: R5 fused kernel (245us), used if ws too small ----------------
__global__ __launch_bounds__(512, 2)
void k_glu(const float* __restrict__ x, const u32x4* __restrict__ wcomb,
           float* __restrict__ y) {
    __shared__ u32x4 smem[9216];
    const int tid  = threadIdx.x;
    const int lane = tid & 63;
    const int w    = tid >> 6;
    const int q    = lane >> 5;
    const int l31  = lane & 31;
    const int g    = blockIdx.x & 7;
    const int m0   = g * TGRP + (blockIdx.x >> 3) * 256;
    const int tok  = m0 + w * 32 + l31;
    const u32x4* wcg = wcomb + (size_t)(g * 32) * 3072;
    #pragma unroll
    for (int i = 0; i < 6; ++i) { int off = i * 512 + w * 64; g2l(wcg + off + lane, smem + off); }
    #pragma unroll
    for (int i = 0; i < 6; ++i) { int off = i * 512 + w * 64; g2l(wcg + 3072 + off + lane, smem + 3072 + off); }
    u32x4 xf[16];
    {
        const float* xrow = x + (size_t)tok * DMODEL + q * 8;
        #pragma unroll
        for (int ks = 0; ks < 16; ++ks) {
            float4 a = *(const float4*)(xrow + ks * 16);
            float4 b = *(const float4*)(xrow + ks * 16 + 4);
            xf[ks] = u32x4{ cvtpk(a.x, a.y), cvtpk(a.z, a.w), cvtpk(b.x, b.y), cvtpk(b.z, b.w) };
        }
    }
    f32x16 acc[8];
    #pragma unroll
    for (int nb = 0; nb < 8; ++nb)
        #pragma unroll
        for (int i = 0; i < 16; ++i) acc[nb][i] = 0.0f;
    asm volatile("s_waitcnt vmcnt(0)" ::: "memory");
    __builtin_amdgcn_s_barrier();
    asm volatile("" ::: "memory");
    u32x4 A0, A1;
    {
        const u32x4* sb = smem;
        f32x16 zg, zu;
        #pragma unroll
        for (int i = 0; i < 16; ++i) { zg[i] = 0.0f; zu[i] = 0.0f; }
        #pragma unroll
        for (int ks = 0; ks < 16; ++ks) {
            const u32x4 a1 = sb[ks * 64 + lane];
            const u32x4 a2 = sb[1024 + ks * 64 + lane];
            zg = MFMA(a1, xf[ks], zg);
            zu = MFMA(a2, xf[ks], zu);
        }
        float hv[16];
        #pragma unroll
        for (int i = 0; i < 16; ++i) {
            const float gv = zg[i];
            const float s  = __builtin_amdgcn_rcpf(1.0f + __expf(-gv));
            hv[i] = gv * s * zu[i];
        }
        A0 = u32x4{ cvtpk(hv[0], hv[1]), cvtpk(hv[2], hv[3]), cvtpk(hv[4], hv[5]), cvtpk(hv[6], hv[7]) };
        A1 = u32x4{ cvtpk(hv[8], hv[9]), cvtpk(hv[10], hv[11]), cvtpk(hv[12], hv[13]), cvtpk(hv[14], hv[15]) };
    }
    int bc = 1, bp = 0, bn = 2;
    for (int c = 1; c < NCHUNK; ++c) {
        const u32x4* sbc = smem + bc * 3072;
        const u32x4* sbp = smem + bp * 3072;
        asm volatile("s_waitcnt vmcnt(0)" ::: "memory");
        __builtin_amdgcn_s_barrier();
        asm volatile("" ::: "memory");
        if (c + 1 < NCHUNK) {
            u32x4* db = smem + bn * 3072;
            const u32x4* gsrc = wcg + (size_t)(c + 1) * 3072;
            #pragma unroll
            for (int i = 0; i < 6; ++i) { int off = i * 512 + w * 64; g2l(gsrc + off + lane, db + off); }
        }
        f32x16 zg, zu;
        #pragma unroll
        for (int i = 0; i < 16; ++i) { zg[i] = 0.0f; zu[i] = 0.0f; }
        #pragma unroll
        for (int ks = 0; ks < 16; ++ks) {
            const u32x4 a1 = sbc[ks * 64 + lane];
            const u32x4 a2 = sbc[1024 + ks * 64 + lane];
            const u32x4 bd = sbp[2048 + ks * 64 + lane];
            zg = MFMA(a1, xf[ks], zg);
            zu = MFMA(a2, xf[ks], zu);
            if (ks < 8) acc[ks]     = MFMA(A0, bd, acc[ks]);
            else        acc[ks - 8] = MFMA(A1, bd, acc[ks - 8]);
        }
        float hv[16];
        #pragma unroll
        for (int i = 0; i < 16; ++i) {
            const float gv = zg[i];
            const float s  = __builtin_amdgcn_rcpf(1.0f + __expf(-gv));
            hv[i] = gv * s * zu[i];
        }
        A0 = u32x4{ cvtpk(hv[0], hv[1]), cvtpk(hv[2], hv[3]), cvtpk(hv[4], hv[5]), cvtpk(hv[6], hv[7]) };
        A1 = u32x4{ cvtpk(hv[8], hv[9]), cvtpk(hv[10], hv[11]), cvtpk(hv[12], hv[13]), cvtpk(hv[14], hv[15]) };
        const int t = bp; bp = bc; bc = bn; bn = t;
    }
    {
        const u32x4* sbp = smem + bp * 3072;
        #pragma unroll
        for (int ks = 0; ks < 16; ++ks) {
            const u32x4 bd = sbp[2048 + ks * 64 + lane];
            if (ks < 8) acc[ks]     = MFMA(A0, bd, acc[ks]);
            else        acc[ks - 8] = MFMA(A1, bd, acc[ks - 8]);
        }
    }
    float* yp = y + (size_t)(m0 + w * 32) * DMODEL;
    #pragma unroll
    for (int nb = 0; nb < 8; ++nb) {
        const int col = nb * 32 + l31;
        #pragma unroll
        for (int r = 0; r < 16; ++r) {
            const int row = (r & 3) + (r >> 2) * 8 + q * 4;
            yp[(size_t)row * DMODEL + col] = acc[nb][r];
        }
    }
}

extern "C" void kernel_launch(void* const* d_in, const int* in_sizes, int n_in,
                              void* d_out, int out_size, void* d_ws, size_t ws_size,
                              hipStream_t stream) {
    const float* x  = (const float*)d_in[0];
    const float* wg = (const float*)d_in[1];
    const float* wu = (const float*)d_in[2];
    const float* wd = (const float*)d_in[3];
    float* y = (float*)d_out;

    u32x4* wcomb = (u32x4*)d_ws;                 // 786432 u32x4 = 12.6 MB
    u32x4* hbuf  = wcomb + 786432;               // 4096*64*64 u32x4 = 268.4 MB

    const size_t need = (size_t)786432 * 16 + (size_t)4096 * 64 * 64 * 16;

    k_prep_w<<<dim3(3072), dim3(256), 0, stream>>>(wg, wu, wd, wcomb);
    if (ws_size >= need) {
        k_gemm1<<<dim3(256), dim3(512), 0, stream>>>(x, wcomb, hbuf);
        k_gemm2<<<dim3(512), dim3(512), 0, stream>>>(hbuf, wcomb, y);
    } else {
        k_glu<<<dim3(512), dim3(512), 0, stream>>>(x, wcomb, y);
    }
}

// Round 9
// 409.110 us; speedup vs baseline: 1.3872x; 1.3872x over previous
//
#include <hip/hip_runtime.h>

typedef __bf16 bf16x8 __attribute__((ext_vector_type(8)));
typedef float f32x16 __attribute__((ext_vector_type(16)));
typedef unsigned int u32x4 __attribute__((ext_vector_type(4)));

#define NGROUP 8
#define DMODEL 256
#define DFF    1024
#define TTOT   131072
#define TGRP   (TTOT / NGROUP)   // 16384
#define MTILE  256               // tokens per block (8 waves x 32)
#define NCHUNK 32                // f-chunks of 32 (DFF/32)
// LDS map (96 KB): two 48KB chunk buffers (double-buffered).
//   buf b at byte offset b*49152:
//     [   0, 16K)  gate A-frags [ks(16)][lane(64)] x 16B
//     [ 16K, 32K)  up   A-frags
//     [ 32K, 48K)  down B-frags [fi(16)][lane(64)] x 16B (k-permuted at prep)
//
// KEY FIX (R8 diagnosis): C++ LDS reads after a g2l issue get a
// compiler-inserted s_waitcnt vmcnt(0) (conservative aliasing vs the
// global_load_lds LDS writes) -- every prior round actually ran
// serial {drain staging -> compute}.  All in-loop LDS reads are now
// OPAQUE inline-asm ds_read_b128 with manual lgkmcnt + sched_barrier
// (rule #18), so stage(c+1) truly overlaps compute(c).

__device__ __forceinline__ unsigned int f2bf(float f) {
    unsigned int x = __builtin_bit_cast(unsigned int, f);
    return (x + 0x7fffu + ((x >> 16) & 1u)) >> 16;   // RNE
}
__device__ __forceinline__ unsigned int pack2(float lo, float hi) {
    return f2bf(lo) | (f2bf(hi) << 16);
}
__device__ __forceinline__ unsigned int cvtpk(float lo, float hi) {
    unsigned int r;
    asm("v_cvt_pk_bf16_f32 %0, %1, %2" : "=v"(r) : "v"(lo), "v"(hi));  // RNE
    return r;
}

__device__ __forceinline__ void g2l(const void* g, void* l) {
    __builtin_amdgcn_global_load_lds(
        (const __attribute__((address_space(1))) unsigned int*)g,
        (__attribute__((address_space(3))) unsigned int*)l, 16, 0, 0);
}

// Opaque LDS read: addr is a byte offset from LDS base (smem starts at 0).
// Not ordered vs g2l by the compiler; consumer must lgkmcnt+sched_barrier.
__device__ __forceinline__ u32x4 dsr(unsigned addr) {
    u32x4 d;
    asm volatile("ds_read_b128 %0, %1" : "=v"(d) : "v"(addr));
    return d;
}
#define WAITLGKM(n) asm volatile("s_waitcnt lgkmcnt(" #n ")")
#define SBAR0()     __builtin_amdgcn_sched_barrier(0)

#define MFMA(A, B, C) __builtin_amdgcn_mfma_f32_32x32x16_bf16( \
        __builtin_bit_cast(bf16x8, A), __builtin_bit_cast(bf16x8, B), C, 0, 0, 0)

// ---------------- prep: all weights -> per-(group,chunk) 48KB frag blocks ----------------
//   fid 0..15  : gate A-frag, ks=fid      W[d=ks*16+q*8+j][f=c*32+l31]
//   fid 16..31 : up   A-frag, ks=fid-16
//   fid 32..47 : down B-frag, ks2=(fid-32)>>3, nb=(fid-32)&7
//     k-axis PERMUTED to match packed-accumulator A-frags:
//     B[k=q*8+j] = Wd[F = c*32 + ks2*16 + q*4 + (j&3) + 8*(j>>2)][col=nb*32+l31]
__global__ void k_prep_w(const float* __restrict__ wg, const float* __restrict__ wu,
                         const float* __restrict__ wd, u32x4* __restrict__ out) {
    int t = blockIdx.x * 256 + threadIdx.x;   // 786432 total
    int lane = t & 63;
    int q = lane >> 5, l31 = lane & 31;
    int fg = t >> 6;
    int fid = fg % 48;
    int gc  = fg / 48;
    int c = gc & 31, g = gc >> 5;
    u32x4 v;
    if (fid < 32) {
        const float* w = (fid < 16) ? wg : wu;
        int ks = fid & 15;
        const float* src = w + (size_t)(g * 256 + ks * 16 + q * 8) * 1024 + c * 32 + l31;
        v = u32x4{ pack2(src[0],        src[1024]),
                   pack2(src[2 * 1024], src[3 * 1024]),
                   pack2(src[4 * 1024], src[5 * 1024]),
                   pack2(src[6 * 1024], src[7 * 1024]) };
    } else {
        int idx = fid - 32;
        int ks2 = idx >> 3, nb = idx & 7;
        const float* src = wd + (size_t)(g * 1024 + c * 32 + ks2 * 16 + q * 4) * 256 + nb * 32 + l31;
        v = u32x4{ pack2(src[0 * 256],  src[1 * 256]),
                   pack2(src[2 * 256],  src[3 * 256]),
                   pack2(src[8 * 256],  src[9 * 256]),
                   pack2(src[10 * 256], src[11 * 256]) };
    }
    out[t] = v;
}

// ---------------- main fused grouped-GLU ----------------
__global__ __launch_bounds__(512, 2)
void k_glu(const float* __restrict__ x,      // fp32 x row-major [T][256]
           const u32x4* __restrict__ wcomb,  // [g][c][48 frag-groups][64 lanes]
           float* __restrict__ y) {
    __shared__ u32x4 smem[6144];   // 96 KB: two 48KB buffers

    const int tid  = threadIdx.x;
    const int lane = tid & 63;
    const int w    = tid >> 6;      // wave 0..7 = token-32 block
    const int q    = lane >> 5;
    const int l31  = lane & 31;

    // XCD swizzle: group = blockIdx & 7 so each XCD's L2 holds one group's weights
    const int g    = blockIdx.x & 7;
    const int m0   = g * TGRP + (blockIdx.x >> 3) * MTILE;
    const int tok  = m0 + w * 32 + l31;

    const u32x4* wcg = wcomb + (size_t)(g * 32) * 3072;
    const unsigned lbase = (unsigned)lane * 16u;   // LDS byte offset of this lane's 16B

    // ---- prologue: stage chunk 0 -> buf0 (6 g2l per wave)
    #pragma unroll
    for (int i = 0; i < 6; ++i) {
        int off = i * 512 + w * 64;   // u32x4 index, wave-uniform LDS dest
        g2l(wcg + off + lane, smem + off);
    }
    // x -> bf16 B-frags, register-resident for the whole block
    u32x4 xf[16];
    {
        const float* xrow = x + (size_t)tok * DMODEL + q * 8;
        #pragma unroll
        for (int ks = 0; ks < 16; ++ks) {
            float4 a = *(const float4*)(xrow + ks * 16);
            float4 b = *(const float4*)(xrow + ks * 16 + 4);
            xf[ks] = u32x4{ cvtpk(a.x, a.y), cvtpk(a.z, a.w),
                            cvtpk(b.x, b.y), cvtpk(b.z, b.w) };
        }
    }

    f32x16 acc[8];
    #pragma unroll
    for (int nb = 0; nb < 8; ++nb)
        #pragma unroll
        for (int i = 0; i < 16; ++i) acc[nb][i] = 0.0f;

    for (int c = 0; c < NCHUNK; ++c) {
        // stage(c) was issued a full chunk ago -> drain is cheap now
        asm volatile("s_waitcnt vmcnt(0)" ::: "memory");
        __builtin_amdgcn_s_barrier();      // publish buf c; all readers of other buf done
        asm volatile("" ::: "memory");

        // issue stage(c+1) -- overlaps the entire compute below (opaque ds_reads!)
        if (c + 1 < NCHUNK) {
            u32x4* db = smem + ((c + 1) & 1) * 3072;
            const u32x4* gsrc = wcg + (size_t)(c + 1) * 3072;
            #pragma unroll
            for (int i = 0; i < 6; ++i) {
                int off = i * 512 + w * 64;
                g2l(gsrc + off + lane, db + off);
            }
        }

        const unsigned bb = (unsigned)((c & 1) * 49152) + lbase;

        // ---- GEMM1: z^T over K=256; asm ds_reads, depth-1 pipelined
        f32x16 zg, zu;
        #pragma unroll
        for (int i = 0; i < 16; ++i) { zg[i] = 0.0f; zu[i] = 0.0f; }
        u32x4 pa[2], pb[2];
        pa[0] = dsr(bb);
        pb[0] = dsr(bb + 16384u);
        __builtin_amdgcn_s_setprio(1);
        #pragma unroll
        for (int ks = 0; ks < 16; ++ks) {
            if (ks < 15) {
                pa[(ks + 1) & 1] = dsr(bb + (unsigned)(ks + 1) * 1024u);
                pb[(ks + 1) & 1] = dsr(bb + 16384u + (unsigned)(ks + 1) * 1024u);
                WAITLGKM(2);               // pair(ks) complete; pair(ks+1) in flight
            } else {
                WAITLGKM(0);
            }
            SBAR0();
            zg = MFMA(pa[ks & 1], xf[ks], zg);
            zu = MFMA(pb[ks & 1], xf[ks], zu);
        }
        __builtin_amdgcn_s_setprio(0);

        // ---- act: h = silu(zg)*zu, packed in-register (A-frag == natural reg order)
        float hv[16];
        #pragma unroll
        for (int i = 0; i < 16; ++i) {
            const float gv = zg[i];
            const float s  = __builtin_amdgcn_rcpf(1.0f + __expf(-gv));
            hv[i] = gv * s * zu[i];
        }
        const u32x4 A0 = u32x4{ cvtpk(hv[0], hv[1]),   cvtpk(hv[2], hv[3]),
                                cvtpk(hv[4], hv[5]),   cvtpk(hv[6], hv[7]) };
        const u32x4 A1 = u32x4{ cvtpk(hv[8], hv[9]),   cvtpk(hv[10], hv[11]),
                                cvtpk(hv[12], hv[13]), cvtpk(hv[14], hv[15]) };

        // ---- GEMM2: acc += h * Wd(chunk c); asm ds_reads, depth-1 pipelined
        u32x4 pd[2];
        pd[0] = dsr(bb + 32768u);
        __builtin_amdgcn_s_setprio(1);
        #pragma unroll
        for (int fi = 0; fi < 16; ++fi) {
            if (fi < 15) {
                pd[(fi + 1) & 1] = dsr(bb + 32768u + (unsigned)(fi + 1) * 1024u);
                WAITLGKM(1);               // pd(fi) complete
            } else {
                WAITLGKM(0);
            }
            SBAR0();
            if (fi < 8) acc[fi]     = MFMA(A0, pd[fi & 1], acc[fi]);
            else        acc[fi - 8] = MFMA(A1, pd[fi & 1], acc[fi - 8]);
        }
        __builtin_amdgcn_s_setprio(0);
    }

    // epilogue: C layout -> y fp32
    float* yp = y + (size_t)(m0 + w * 32) * DMODEL;
    #pragma unroll
    for (int nb = 0; nb < 8; ++nb) {
        const int col = nb * 32 + l31;
        #pragma unroll
        for (int r = 0; r < 16; ++r) {
            const int row = (r & 3) + (r >> 2) * 8 + q * 4;
            yp[(size_t)row * DMODEL + col] = acc[nb][r];
        }
    }
}

extern "C" void kernel_launch(void* const* d_in, const int* in_sizes, int n_in,
                              void* d_out, int out_size, void* d_ws, size_t ws_size,
                              hipStream_t stream) {
    const float* x  = (const float*)d_in[0];
    const float* wg = (const float*)d_in[1];
    const float* wu = (const float*)d_in[2];
    const float* wd = (const float*)d_in[3];
    float* y = (float*)d_out;

    // ws: wcomb only (12.6 MB); x is consumed fp32 directly by k_glu
    u32x4* wcomb = (u32x4*)d_ws;   // 8*32*48*64 = 786432 u32x4

    k_prep_w<<<dim3(3072), dim3(256), 0, stream>>>(wg, wu, wd, wcomb);
    k_glu<<<dim3(512), dim3(512), 0, stream>>>(x, wcomb, y);
}